// Round 1
// baseline (904.825 us; speedup 1.0000x reference)
//
#include <hip/hip_runtime.h>
#include <hip/hip_bf16.h>

typedef __bf16 bf16x8 __attribute__((ext_vector_type(8)));
typedef float f32x4 __attribute__((ext_vector_type(4)));

#define D 128           // D_IN == D_OUT == 128
#define EDIM 16
#define CAP 40          // bucket capacity (deg ~ Poisson(8); P(any>40) ~ 1e-10)

__device__ inline unsigned short f2bf(float f) {   // RTNE fp32 -> bf16
    unsigned u = __builtin_bit_cast(unsigned, f);
    u += 0x7fffu + ((u >> 16) & 1u);
    return (unsigned short)(u >> 16);
}

// ---------------------------------------------------------------------------
// Kernel 1: bucketed CSR inversion, src packed into the slot.
// ---------------------------------------------------------------------------
__global__ __launch_bounds__(256) void fill_buckets(
    const int* __restrict__ ei,   // [2,E] int32
    int* __restrict__ deg,        // [N]
    int2* __restrict__ perm2,     // [N*CAP] {edge id, src}
    int E)
{
    const int e = blockIdx.x * 256 + threadIdx.x;
    if (e >= E) return;
    const int src = ei[e];
    const int dst = ei[(size_t)E + e];
    const int pos = atomicAdd(&deg[dst], 1);
    if (pos < CAP) perm2[(size_t)dst * CAP + pos] = make_int2(e, src);
}

// ---------------------------------------------------------------------------
// Kernel 2: xw = x @ W (fp32 in, on-the-fly bf16, MFMA 16x16x32, bf16 out).
// ---------------------------------------------------------------------------
__global__ __launch_bounds__(256) void gemm_xw(
    const float* __restrict__ x,        // [N,128] fp32
    const float* __restrict__ W,        // [128,128] fp32
    unsigned short* __restrict__ xwb,   // [N,128] bf16
    int ntiles)
{
    __shared__ unsigned short Wt[128][136];
    const int t = threadIdx.x;

    #pragma unroll
    for (int i = 0; i < 16; ++i) {
        int id = (i * 256 + t) * 4;            // 4 consecutive n at row k
        float4 p = *(const float4*)(W + id);
        int k = id >> 7, n = id & 127;
        Wt[n + 0][k] = f2bf(p.x);
        Wt[n + 1][k] = f2bf(p.y);
        Wt[n + 2][k] = f2bf(p.z);
        Wt[n + 3][k] = f2bf(p.w);
    }
    __syncthreads();

    const int wave = t >> 6, lane = t & 63;
    const int quad = lane >> 4, low = lane & 15;
    const int nwaves = gridDim.x * 4;

    for (int mt = blockIdx.x * 4 + wave; mt < ntiles; mt += nwaves) {
        const int arow = mt * 16 + low;
        f32x4 acc[8];
        #pragma unroll
        for (int nt = 0; nt < 8; ++nt) acc[nt] = (f32x4){0.f, 0.f, 0.f, 0.f};

        #pragma unroll
        for (int kc = 0; kc < 4; ++kc) {
            const int k0 = kc * 32 + quad * 8;
            const float* xp = x + (size_t)arow * D + k0;
            float4 a0 = *(const float4*)xp;
            float4 a1 = *(const float4*)(xp + 4);
            union { unsigned short us[8]; bf16x8 v; } a;
            a.us[0] = f2bf(a0.x); a.us[1] = f2bf(a0.y);
            a.us[2] = f2bf(a0.z); a.us[3] = f2bf(a0.w);
            a.us[4] = f2bf(a1.x); a.us[5] = f2bf(a1.y);
            a.us[6] = f2bf(a1.z); a.us[7] = f2bf(a1.w);
            #pragma unroll
            for (int nt = 0; nt < 8; ++nt) {
                bf16x8 bf = *(const bf16x8*)(&Wt[nt * 16 + low][k0]);
                acc[nt] = __builtin_amdgcn_mfma_f32_16x16x32_bf16(a.v, bf, acc[nt], 0, 0, 0);
            }
        }
        #pragma unroll
        for (int nt = 0; nt < 8; ++nt) {
            #pragma unroll
            for (int r = 0; r < 4; ++r) {
                const size_t row = (size_t)mt * 16 + quad * 4 + r;
                xwb[row * D + nt * 16 + low] = f2bf(acc[nt][r]);
            }
        }
    }
}

// ---------------------------------------------------------------------------
// Kernel 3: gather-side reduction, one wave per node, per-edge M form:
//   m[ch]  = sum_k ea[e][k] * ew[k][ch]     (16 fmac / lane-channel)
//   out[ch] += m[ch] * xw[src][ch]          (1 fma)
// No g[32] accumulator array, no epilogue -> c0/c1 stay register-resident.
// All bucket metadata goes through the SCALAR pipe (readfirstlane'd node
// index -> s_load for deg/perm2/ea).  Depth-3 node pipeline per wave:
//   iter(n): s_load slots(n+2) | issue gathers(n+1) | fmac node n
// so gather + metadata latency hides under the previous node's compute.
// OOB slots clamp to row 0 (always valid); only the accumulate is predicated.
// ---------------------------------------------------------------------------
#define EDGE1(I, SL, XV, OFF, DG)                                            \
    {                                                                        \
        const bool act_ = ((OFF) + (I)) < (DG);                              \
        const int e_ = act_ ? (SL)[(I)].x : 0;                               \
        const unsigned xv_ = (XV)[(I)];                                      \
        const float4* er_ = (const float4*)(ea + (size_t)(unsigned)e_ * EDIM); \
        const float4 r0_ = er_[0], r1_ = er_[1], r2_ = er_[2], r3_ = er_[3]; \
        float m0_ = r0_.x * c0[0];                                           \
        m0_ = fmaf(r0_.y, c0[1],  m0_); m0_ = fmaf(r0_.z, c0[2],  m0_);      \
        m0_ = fmaf(r0_.w, c0[3],  m0_); m0_ = fmaf(r1_.x, c0[4],  m0_);      \
        m0_ = fmaf(r1_.y, c0[5],  m0_); m0_ = fmaf(r1_.z, c0[6],  m0_);      \
        m0_ = fmaf(r1_.w, c0[7],  m0_); m0_ = fmaf(r2_.x, c0[8],  m0_);      \
        m0_ = fmaf(r2_.y, c0[9],  m0_); m0_ = fmaf(r2_.z, c0[10], m0_);      \
        m0_ = fmaf(r2_.w, c0[11], m0_); m0_ = fmaf(r3_.x, c0[12], m0_);      \
        m0_ = fmaf(r3_.y, c0[13], m0_); m0_ = fmaf(r3_.z, c0[14], m0_);      \
        m0_ = fmaf(r3_.w, c0[15], m0_);                                      \
        float m1_ = r0_.x * c1[0];                                           \
        m1_ = fmaf(r0_.y, c1[1],  m1_); m1_ = fmaf(r0_.z, c1[2],  m1_);      \
        m1_ = fmaf(r0_.w, c1[3],  m1_); m1_ = fmaf(r1_.x, c1[4],  m1_);      \
        m1_ = fmaf(r1_.y, c1[5],  m1_); m1_ = fmaf(r1_.z, c1[6],  m1_);      \
        m1_ = fmaf(r1_.w, c1[7],  m1_); m1_ = fmaf(r2_.x, c1[8],  m1_);      \
        m1_ = fmaf(r2_.y, c1[9],  m1_); m1_ = fmaf(r2_.z, c1[10], m1_);      \
        m1_ = fmaf(r2_.w, c1[11], m1_); m1_ = fmaf(r3_.x, c1[12], m1_);      \
        m1_ = fmaf(r3_.y, c1[13], m1_); m1_ = fmaf(r3_.z, c1[14], m1_);      \
        m1_ = fmaf(r3_.w, c1[15], m1_);                                      \
        if (act_) {                                                          \
            const float xlo_ = __builtin_bit_cast(float, xv_ << 16);         \
            const float xhi_ = __builtin_bit_cast(float, xv_ & 0xffff0000u); \
            a0 = fmaf(m0_, xlo_, a0);                                        \
            a1 = fmaf(m1_, xhi_, a1);                                        \
        }                                                                    \
    }

__global__ __launch_bounds__(256, 4) void gather_out(
    const float* __restrict__ ea,          // [E,16] fp32
    const float* __restrict__ ew,          // [16,128] fp32
    const unsigned short* __restrict__ xwb,// [N,128] bf16
    const int* __restrict__ deg,           // [N]
    const int2* __restrict__ perm2,        // [N*CAP] {e, src}
    const float* __restrict__ b,           // [128]
    float* __restrict__ out,               // [N,128] fp32
    int N)
{
    const int t = threadIdx.x, wave = t >> 6, lane = t & 63;
    const int ch = lane * 2;

    float c0[16], c1[16];
    #pragma unroll
    for (int k = 0; k < 16; ++k) {
        c0[k] = ew[k * D + ch];
        c1[k] = ew[k * D + ch + 1];
    }
    const float b0 = b[ch], b1 = b[ch + 1];
    const int nw = gridDim.x * 4;

    int n = blockIdx.x * 4 + wave;
    if (n >= N) return;

    // ---- pipeline bootstrap: stage A (node n), stage B (node n+nw) ----
    int nbA = __builtin_amdgcn_readfirstlane(n);
    int dgA = deg[nbA]; dgA = dgA < CAP ? dgA : CAP;      // scalar load
    int2 slA[8];
    {
        const int2* pp = perm2 + (size_t)nbA * CAP;
        #pragma unroll
        for (int i = 0; i < 8; ++i) slA[i] = pp[i];       // s_load (uniform addr)
    }

    int n1 = n + nw;
    int nbB = 0, dgB = 0;
    int2 slB[8];
    if (n1 < N) {
        nbB = __builtin_amdgcn_readfirstlane(n1);
        dgB = deg[nbB]; dgB = dgB < CAP ? dgB : CAP;
        const int2* pp = perm2 + (size_t)nbB * CAP;
        #pragma unroll
        for (int i = 0; i < 8; ++i) slB[i] = pp[i];
    } else {
        #pragma unroll
        for (int i = 0; i < 8; ++i) slB[i] = make_int2(0, 0);
    }

    // gathers for stage A
    unsigned xvA[8];
    #pragma unroll
    for (int i = 0; i < 8; ++i) {
        const int s = (i < dgA) ? slA[i].y : 0;           // clamp -> always valid
        xvA[i] = *(const unsigned*)(xwb + (size_t)(unsigned)s * D + ch);
    }

    for (;;) {
        // 1. prefetch stage C metadata (node n + 2*nw): scalar loads in flight
        const int n2 = n1 + nw;
        int nbC = 0, dgC = 0;
        int2 slC[8];
        if (n2 < N) {
            nbC = __builtin_amdgcn_readfirstlane(n2);
            dgC = deg[nbC]; dgC = dgC < CAP ? dgC : CAP;
            const int2* pp = perm2 + (size_t)nbC * CAP;
            #pragma unroll
            for (int i = 0; i < 8; ++i) slC[i] = pp[i];
        } else {
            #pragma unroll
            for (int i = 0; i < 8; ++i) slC[i] = make_int2(0, 0);
        }

        // 2. issue xw gathers for stage B (slots arrived during last iter)
        unsigned xvB[8];
        #pragma unroll
        for (int i = 0; i < 8; ++i) {
            const int s = (i < dgB) ? slB[i].y : 0;
            xvB[i] = *(const unsigned*)(xwb + (size_t)(unsigned)s * D + ch);
        }

        // 3. process current node (stage A) — hides (1) and (2) latency
        float a0 = b0, a1 = b1;

        const bool moreA = dgA > 8;
        int2 slX[8];
        if (moreA) {                                      // 2nd-batch slots early
            const int2* pp = perm2 + (size_t)nbA * CAP + 8;
            #pragma unroll
            for (int i = 0; i < 8; ++i) slX[i] = pp[i];
        }

        #pragma unroll
        for (int i = 0; i < 4; ++i) EDGE1(i, slA, xvA, 0, dgA)

        unsigned xvX[8];
        if (moreA) {                                      // issue mid-compute
            #pragma unroll
            for (int i = 0; i < 8; ++i) {
                const int s = (8 + i < dgA) ? slX[i].y : 0;
                xvX[i] = *(const unsigned*)(xwb + (size_t)(unsigned)s * D + ch);
            }
        }

        if (dgA > 4) {
            #pragma unroll
            for (int i = 4; i < 8; ++i) EDGE1(i, slA, xvA, 0, dgA)
        }

        if (moreA) {
            #pragma unroll
            for (int i = 0; i < 4; ++i) EDGE1(i, slX, xvX, 8, dgA)
            if (dgA > 12) {
                #pragma unroll
                for (int i = 4; i < 8; ++i) EDGE1(i, slX, xvX, 8, dgA)
            }
            // rare tail: deg in (16, CAP]
            for (int base = 16; base < dgA; base += 8) {
                const int2* pp = perm2 + (size_t)nbA * CAP + base;
                int2 slY[8];
                #pragma unroll
                for (int i = 0; i < 8; ++i) slY[i] = pp[i];
                unsigned xvY[8];
                #pragma unroll
                for (int i = 0; i < 8; ++i) {
                    const int s = (base + i < dgA) ? slY[i].y : 0;
                    xvY[i] = *(const unsigned*)(xwb + (size_t)(unsigned)s * D + ch);
                }
                #pragma unroll
                for (int i = 0; i < 8; ++i) EDGE1(i, slY, xvY, base, dgA)
            }
        }

        *(float2*)(out + (size_t)n * D + ch) = make_float2(a0, a1);

        if (n1 >= N) break;

        // 4. rotate pipeline state
        n = n1; n1 = n2;
        nbA = nbB; dgA = dgB;
        #pragma unroll
        for (int i = 0; i < 8; ++i) { slA[i] = slB[i]; xvA[i] = xvB[i]; slB[i] = slC[i]; }
        nbB = nbC; dgB = dgC;
    }
}

extern "C" void kernel_launch(void* const* d_in, const int* in_sizes, int n_in,
                              void* d_out, int out_size, void* d_ws, size_t ws_size,
                              hipStream_t stream) {
    const float* x  = (const float*)d_in[0];
    const int*   ei = (const int*)d_in[1];
    const float* ea = (const float*)d_in[2];
    const float* W  = (const float*)d_in[3];
    const float* ew = (const float*)d_in[4];
    const float* bb = (const float*)d_in[5];
    float* out = (float*)d_out;

    const int N = in_sizes[0] / D;        // 100000
    const int E = in_sizes[2] / EDIM;     // 800000

    // ws: xwb bf16 25.6MB | deg 0.4MB | perm2 int2 32MB  (~58MB)
    unsigned short* xwb = (unsigned short*)d_ws;
    int* deg   = (int*)(xwb + (size_t)N * D);
    int2* perm2 = (int2*)(deg + N);

    hipMemsetAsync(deg, 0, (size_t)N * sizeof(int), stream);
    fill_buckets<<<(E + 255) / 256, 256, 0, stream>>>(ei, deg, perm2, E);

    const int ntiles = N / 16;            // 6250 exact
    gemm_xw<<<1024, 256, 0, stream>>>(x, W, xwb, ntiles);

    gather_out<<<6144, 256, 0, stream>>>(ea, ew, xwb, deg, perm2, bb, out, N);
}

// Round 2
// 382.172 us; speedup vs baseline: 2.3676x; 2.3676x over previous
//
#include <hip/hip_runtime.h>
#include <hip/hip_bf16.h>

typedef __bf16 bf16x8 __attribute__((ext_vector_type(8)));
typedef float f32x4 __attribute__((ext_vector_type(4)));

#define D 128           // D_IN == D_OUT == 128
#define EDIM 16
#define CAP 40          // bucket capacity (deg ~ Poisson(8); P(any>40) ~ 1e-10)

__device__ inline unsigned short f2bf(float f) {   // RTNE fp32 -> bf16
    unsigned u = __builtin_bit_cast(unsigned, f);
    u += 0x7fffu + ((u >> 16) & 1u);
    return (unsigned short)(u >> 16);
}

// ---------------------------------------------------------------------------
// Kernel 1: bucketed CSR inversion, src packed into the slot.
// ---------------------------------------------------------------------------
__global__ __launch_bounds__(256) void fill_buckets(
    const int* __restrict__ ei,   // [2,E] int32
    int* __restrict__ deg,        // [N]
    int2* __restrict__ perm2,     // [N*CAP] {edge id, src}
    int E)
{
    const int e = blockIdx.x * 256 + threadIdx.x;
    if (e >= E) return;
    const int src = ei[e];
    const int dst = ei[(size_t)E + e];
    const int pos = atomicAdd(&deg[dst], 1);
    if (pos < CAP) perm2[(size_t)dst * CAP + pos] = make_int2(e, src);
}

// ---------------------------------------------------------------------------
// Kernel 2: xw = x @ W (fp32 in, on-the-fly bf16, MFMA 16x16x32, bf16 out).
// ---------------------------------------------------------------------------
__global__ __launch_bounds__(256) void gemm_xw(
    const float* __restrict__ x,        // [N,128] fp32
    const float* __restrict__ W,        // [128,128] fp32
    unsigned short* __restrict__ xwb,   // [N,128] bf16
    int ntiles)
{
    __shared__ unsigned short Wt[128][136];
    const int t = threadIdx.x;

    #pragma unroll
    for (int i = 0; i < 16; ++i) {
        int id = (i * 256 + t) * 4;            // 4 consecutive n at row k
        float4 p = *(const float4*)(W + id);
        int k = id >> 7, n = id & 127;
        Wt[n + 0][k] = f2bf(p.x);
        Wt[n + 1][k] = f2bf(p.y);
        Wt[n + 2][k] = f2bf(p.z);
        Wt[n + 3][k] = f2bf(p.w);
    }
    __syncthreads();

    const int wave = t >> 6, lane = t & 63;
    const int quad = lane >> 4, low = lane & 15;
    const int nwaves = gridDim.x * 4;

    for (int mt = blockIdx.x * 4 + wave; mt < ntiles; mt += nwaves) {
        const int arow = mt * 16 + low;
        f32x4 acc[8];
        #pragma unroll
        for (int nt = 0; nt < 8; ++nt) acc[nt] = (f32x4){0.f, 0.f, 0.f, 0.f};

        #pragma unroll
        for (int kc = 0; kc < 4; ++kc) {
            const int k0 = kc * 32 + quad * 8;
            const float* xp = x + (size_t)arow * D + k0;
            float4 a0 = *(const float4*)xp;
            float4 a1 = *(const float4*)(xp + 4);
            union { unsigned short us[8]; bf16x8 v; } a;
            a.us[0] = f2bf(a0.x); a.us[1] = f2bf(a0.y);
            a.us[2] = f2bf(a0.z); a.us[3] = f2bf(a0.w);
            a.us[4] = f2bf(a1.x); a.us[5] = f2bf(a1.y);
            a.us[6] = f2bf(a1.z); a.us[7] = f2bf(a1.w);
            #pragma unroll
            for (int nt = 0; nt < 8; ++nt) {
                bf16x8 bf = *(const bf16x8*)(&Wt[nt * 16 + low][k0]);
                acc[nt] = __builtin_amdgcn_mfma_f32_16x16x32_bf16(a.v, bf, acc[nt], 0, 0, 0);
            }
        }
        #pragma unroll
        for (int nt = 0; nt < 8; ++nt) {
            #pragma unroll
            for (int r = 0; r < 4; ++r) {
                const size_t row = (size_t)mt * 16 + quad * 4 + r;
                xwb[row * D + nt * 16 + low] = f2bf(acc[nt][r]);
            }
        }
    }
}

// ---------------------------------------------------------------------------
// Kernel 3: gather-side reduction. TWO waves per node, 64 channels each
// (1 channel per lane).  Per edge, per lane:
//   m  = sum_k ea[e][k] * c[k]      (16 fmac, 2 partial chains)
//   a += m * xw[src][ch]            (1 fma)
// All bucket metadata through the SCALAR pipe: readfirstlane'd node index ->
// s_load for deg + one contiguous 64B s_load for 8 slots (e,src in SGPRs,
// no per-slot readfirstlane) + SGPR-indexed s_load for ea rows.  The xw
// gather is global_load_ushort with SGPR base + one loop-invariant voffset
// (~1 VGPR per in-flight edge).  Lean state (c[16] + xf[8] ~ 45 VGPR) ->
// __launch_bounds__(256,8) = 8 waves/SIMD for latency hiding.
// NO cross-node software pipeline, NO loop-carried arrays (round-1 spilled
// 1.5 GB of scratch that way).
// ---------------------------------------------------------------------------
__global__ __launch_bounds__(256, 8) void gather_out(
    const float* __restrict__ ea,          // [E,16] fp32
    const float* __restrict__ ew,          // [16,128] fp32
    const unsigned short* __restrict__ xwb,// [N,128] bf16
    const int* __restrict__ deg,           // [N]
    const int2* __restrict__ perm2,        // [N*CAP] {e, src}
    const float* __restrict__ b,           // [128]
    float* __restrict__ out,               // [N,128] fp32
    int N)
{
    const int t = threadIdx.x, wave = t >> 6, lane = t & 63;
    const int gw = blockIdx.x * 4 + wave;      // global wave id
    const int ch = (gw & 1) * 64 + lane;       // this wave's channel half

    float c[16];
    #pragma unroll
    for (int k = 0; k < 16; ++k) c[k] = ew[k * D + ch];
    const float bv = b[ch];

    const int nstride = (gridDim.x * 4) >> 1;  // node stride per sweep

    for (int n = gw >> 1; n < N; n += nstride) {
        const int nb = __builtin_amdgcn_readfirstlane(n);
        int dg = deg[nb]; dg = dg < CAP ? dg : CAP;         // s_load (uniform)
        const int2* __restrict__ pp = perm2 + (size_t)nb * CAP;
        float a = bv;

        for (int base = 0; base < dg; base += 8) {
            const int rem = dg - base;                       // >= 1, uniform
            // 8 slots: contiguous 64B uniform load -> SGPRs (s_load_dwordx16)
            int2 sl[8];
            #pragma unroll
            for (int i = 0; i < 8; ++i) sl[i] = pp[base + i];

            // clamp inactive slots (beyond dg is poisoned ws) -> scalar selects
            int e[8], s[8];
            #pragma unroll
            for (int i = 0; i < 8; ++i) {
                const bool act = i < rem;
                e[i] = act ? sl[i].x : 0;
                s[i] = act ? sl[i].y : 0;
            }

            // issue all 8 independent gathers first (SGPR base + v_off(ch))
            float xf[8];
            #pragma unroll
            for (int i = 0; i < 8; ++i) {
                const unsigned short u = xwb[(size_t)(unsigned)s[i] * D + ch];
                const float v = __builtin_bit_cast(float, ((unsigned)u) << 16);
                xf[i] = (i < rem) ? v : 0.f;                 // inactive -> +0
            }

            // per-edge: ea row via SGPR s_loads, 16 fmac in 2 partial chains
            #pragma unroll
            for (int i = 0; i < 8; ++i) {
                const float4* er = (const float4*)(ea + (size_t)(unsigned)e[i] * EDIM);
                const float4 r0 = er[0], r1 = er[1], r2 = er[2], r3 = er[3];
                float p = r0.x * c[0];
                p = fmaf(r0.y, c[1],  p); p = fmaf(r0.z, c[2],  p);
                p = fmaf(r0.w, c[3],  p); p = fmaf(r1.x, c[4],  p);
                p = fmaf(r1.y, c[5],  p); p = fmaf(r1.z, c[6],  p);
                p = fmaf(r1.w, c[7],  p);
                float q = r2.x * c[8];
                q = fmaf(r2.y, c[9],  q); q = fmaf(r2.z, c[10], q);
                q = fmaf(r2.w, c[11], q); q = fmaf(r3.x, c[12], q);
                q = fmaf(r3.y, c[13], q); q = fmaf(r3.z, c[14], q);
                q = fmaf(r3.w, c[15], q);
                a = fmaf(p + q, xf[i], a);
            }
        }

        out[(size_t)n * D + ch] = a;        // 64x4B coalesced per wave
    }
}

extern "C" void kernel_launch(void* const* d_in, const int* in_sizes, int n_in,
                              void* d_out, int out_size, void* d_ws, size_t ws_size,
                              hipStream_t stream) {
    const float* x  = (const float*)d_in[0];
    const int*   ei = (const int*)d_in[1];
    const float* ea = (const float*)d_in[2];
    const float* W  = (const float*)d_in[3];
    const float* ew = (const float*)d_in[4];
    const float* bb = (const float*)d_in[5];
    float* out = (float*)d_out;

    const int N = in_sizes[0] / D;        // 100000
    const int E = in_sizes[2] / EDIM;     // 800000

    // ws: xwb bf16 25.6MB | deg 0.4MB | perm2 int2 32MB  (~58MB)
    unsigned short* xwb = (unsigned short*)d_ws;
    int* deg   = (int*)(xwb + (size_t)N * D);
    int2* perm2 = (int2*)(deg + N);

    hipMemsetAsync(deg, 0, (size_t)N * sizeof(int), stream);
    fill_buckets<<<(E + 255) / 256, 256, 0, stream>>>(ei, deg, perm2, E);

    const int ntiles = N / 16;            // 6250 exact
    gemm_xw<<<1024, 256, 0, stream>>>(x, W, xwb, ntiles);

    gather_out<<<6144, 256, 0, stream>>>(ea, ew, xwb, deg, perm2, bb, out, N);
}